// Round 1
// baseline (1031.436 us; speedup 1.0000x reference)
//
#include <hip/hip_runtime.h>
#include <hip/hip_bf16.h>
#include <cmath>

#define T_TOK 8192
#define HID 1024
#define INTER_D 2816
#define NEXP 8
#define NSLOT (T_TOK * 2)

typedef __bf16 bf16x8 __attribute__((ext_vector_type(8)));
typedef __bf16 bf16x4 __attribute__((ext_vector_type(4)));
typedef float f32x4 __attribute__((ext_vector_type(4)));

#define MFMA(a, b, c) __builtin_amdgcn_mfma_f32_16x16x32_bf16(a, b, c, 0, 0, 0)

// ---- workspace layout (bytes) ----
#define XB_OFF    ((size_t)0)                       // bf16 x [T][H]           16.8 MB
#define WGT_OFF   ((size_t)16777216)                // bf16 wgT [E][I][H]      46.1 MB
#define WUT_OFF   ((size_t)62914560)                // bf16 wuT [E][I][H]      46.1 MB
#define WDT_OFF   ((size_t)109051904)               // bf16 wdT [E][H][I]      46.1 MB
#define INTER_OFF ((size_t)155189248)               // bf16 inter [S][I]       92.3 MB
#define ST_OFF    ((size_t)247463936)               // int slot_token[S]
#define SW_OFF    ((size_t)247529472)               // float slot_w[S]
#define TI_OFF    ((size_t)247595008)               // int topk_idx[T][2]
#define TW_OFF    ((size_t)247660544)               // float topk_w[T][2]
#define CTRL_OFF  ((size_t)247726080)               // counts@0, offs@64, cursor@128
#define WS_NEED   ((size_t)247726336)

__device__ __forceinline__ void async16(const void* g, void* l) {
  __builtin_amdgcn_global_load_lds(
      (const __attribute__((address_space(1))) unsigned int*)g,
      (__attribute__((address_space(3))) unsigned int*)l, 16, 0, 0);
}

// ---------------- router: logits (fp64 accum), top-2, renorm weights --------
__global__ void router_k(const float* __restrict__ x, const float* __restrict__ rw,
                         int* __restrict__ topk_idx, float* __restrict__ topk_w,
                         int* __restrict__ counts) {
  int t = blockIdx.x;
  int lane = threadIdx.x;
  double acc[NEXP];
#pragma unroll
  for (int e = 0; e < NEXP; e++) acc[e] = 0.0;
  const float* xr = x + (size_t)t * HID;
  for (int kk = 0; kk < HID / 64; kk++) {
    int k = kk * 64 + lane;
    double xv = (double)xr[k];
#pragma unroll
    for (int e = 0; e < NEXP; e++) acc[e] += xv * (double)rw[k * NEXP + e];
  }
#pragma unroll
  for (int off = 32; off >= 1; off >>= 1)
#pragma unroll
    for (int e = 0; e < NEXP; e++) acc[e] += __shfl_xor(acc[e], off);
  if (lane == 0) {
    int i0 = 0;
    double v0 = acc[0];
    for (int e = 1; e < NEXP; e++)
      if (acc[e] > v0) { v0 = acc[e]; i0 = e; }
    int i1 = -1;
    double v1 = -1e300;
    for (int e = 0; e < NEXP; e++)
      if (e != i0 && acc[e] > v1) { v1 = acc[e]; i1 = e; }
    // renormalized top-2 softmax weights depend only on the two logits
    double w0 = 1.0 / (1.0 + exp(v1 - v0));
    topk_idx[2 * t] = i0;
    topk_idx[2 * t + 1] = i1;
    topk_w[2 * t] = (float)w0;
    topk_w[2 * t + 1] = (float)(1.0 - w0);
    atomicAdd(&counts[i0], 1);
    atomicAdd(&counts[i1], 1);
  }
}

__global__ void offsets_k(const int* __restrict__ counts, int* __restrict__ offs,
                          int* __restrict__ cursor) {
  if (threadIdx.x == 0) {
    int s = 0;
    for (int e = 0; e < NEXP; e++) {
      offs[e] = s;
      cursor[e] = s;
      s += counts[e];
    }
    offs[NEXP] = s;
  }
}

__global__ void scatter_k(const int* __restrict__ topk_idx, const float* __restrict__ topk_w,
                          int* __restrict__ cursor, int* __restrict__ slot_token,
                          float* __restrict__ slot_w) {
  int t = blockIdx.x * blockDim.x + threadIdx.x;
  if (t >= T_TOK) return;
#pragma unroll
  for (int k = 0; k < 2; k++) {
    int e = topk_idx[2 * t + k];
    int pos = atomicAdd(&cursor[e], 1);
    slot_token[pos] = t;
    slot_w[pos] = topk_w[2 * t + k];
  }
}

// ---------------- fp32 -> bf16 convert (x) ----------------------------------
__global__ void cvtx_k(const float* __restrict__ x, __bf16* __restrict__ xb) {
  int i = blockIdx.x * blockDim.x + threadIdx.x;
  float4 v = ((const float4*)x)[i];
  bf16x4 o;
  o[0] = (__bf16)v.x;
  o[1] = (__bf16)v.y;
  o[2] = (__bf16)v.z;
  o[3] = (__bf16)v.w;
  ((bf16x4*)xb)[i] = o;
}

// ---------------- transpose + convert: in fp32 [R][C] -> out bf16 [C][R] ----
__global__ void transpose_k(const float* __restrict__ in, __bf16* __restrict__ out,
                            int R, int C) {
  __shared__ float tile[32][33];
  size_t mo = (size_t)blockIdx.z * R * C;
  in += mo;
  out += mo;
  int c0 = blockIdx.x * 32, r0 = blockIdx.y * 32;
  int tx = threadIdx.x, ty = threadIdx.y;
#pragma unroll
  for (int i = 0; i < 4; i++)
    tile[ty + i * 8][tx] = in[(size_t)(r0 + ty + i * 8) * C + c0 + tx];
  __syncthreads();
#pragma unroll
  for (int i = 0; i < 4; i++)
    out[(size_t)(c0 + ty + i * 8) * R + r0 + tx] = (__bf16)tile[tx][ty + i * 8];
}

// ---------------- G1: gathered A @ [wgT|wuT], fused swiglu+weight -> inter ---
__global__ __launch_bounds__(256, 2) void g1_k(
    const __bf16* __restrict__ xb, const __bf16* __restrict__ wgT,
    const __bf16* __restrict__ wuT, __bf16* __restrict__ inter,
    const int* __restrict__ slot_token, const float* __restrict__ slot_w,
    const int* __restrict__ counts, const int* __restrict__ offs) {
  int e = blockIdx.z;
  int cnt = counts[e];
  int m0 = blockIdx.y * 128;
  if (m0 >= cnt) return;
  int n0 = blockIdx.x * 128;
  int base = offs[e];

  __shared__ __align__(16) __bf16 As[128][64];
  __shared__ __align__(16) __bf16 Bgs[128][64];
  __shared__ __align__(16) __bf16 Bus[128][64];

  int t = threadIdx.x;
  int lane = t & 63, wv = t >> 6;
  int rbase = t >> 3;       // staging row 0..31 (+i*32)
  int kcol = (t & 7) * 8;   // staging col (elements)

  const __bf16* arow[4];
#pragma unroll
  for (int i = 0; i < 4; i++) {
    int gm = m0 + rbase + i * 32;
    int slot = base + min(gm, cnt - 1);
    arow[i] = xb + (size_t)slot_token[slot] * HID + kcol;
  }
  const __bf16* bg = wgT + ((size_t)e * INTER_D + n0 + rbase) * HID + kcol;
  const __bf16* bu = wuT + ((size_t)e * INTER_D + n0 + rbase) * HID + kcol;

  char* lA = (char*)&As[0][0] + wv * 1024;
  char* lG = (char*)&Bgs[0][0] + wv * 1024;
  char* lU = (char*)&Bus[0][0] + wv * 1024;

  f32x4 accg[16], accu[16];
  f32x4 zero = {0.f, 0.f, 0.f, 0.f};
#pragma unroll
  for (int i = 0; i < 16; i++) {
    accg[i] = zero;
    accu[i] = zero;
  }

  int wm = (wv & 1) * 64, wn = (wv >> 1) * 64;
  int fr = lane & 15, quad = lane >> 4;

  for (int kt = 0; kt < HID / 64; kt++) {
    int k0 = kt * 64;
#pragma unroll
    for (int i = 0; i < 4; i++) {
      async16(arow[i] + k0, lA + i * 4096);
      async16(bg + (size_t)(i * 32) * HID + k0, lG + i * 4096);
      async16(bu + (size_t)(i * 32) * HID + k0, lU + i * 4096);
    }
    __syncthreads();
#pragma unroll
    for (int kk = 0; kk < 2; kk++) {
      bf16x8 a[4], g[4], u[4];
#pragma unroll
      for (int i = 0; i < 4; i++) {
        a[i] = *(const bf16x8*)&As[wm + i * 16 + fr][kk * 32 + quad * 8];
        g[i] = *(const bf16x8*)&Bgs[wn + i * 16 + fr][kk * 32 + quad * 8];
        u[i] = *(const bf16x8*)&Bus[wn + i * 16 + fr][kk * 32 + quad * 8];
      }
#pragma unroll
      for (int i = 0; i < 4; i++)
#pragma unroll
        for (int j = 0; j < 4; j++) {
          accg[i * 4 + j] = MFMA(a[i], g[j], accg[i * 4 + j]);
          accu[i * 4 + j] = MFMA(a[i], u[j], accu[i * 4 + j]);
        }
    }
    __syncthreads();
  }

#pragma unroll
  for (int i = 0; i < 4; i++) {
#pragma unroll
    for (int r = 0; r < 4; r++) {
      int gm = m0 + wm + i * 16 + quad * 4 + r;
      if (gm < cnt) {
        int slot = base + gm;
        float w = slot_w[slot];
        __bf16* orow = inter + (size_t)slot * INTER_D + n0 + wn + fr;
#pragma unroll
        for (int j = 0; j < 4; j++) {
          float gg = accg[i * 4 + j][r];
          float uu = accu[i * 4 + j][r];
          float sg = 1.f / (1.f + __expf(-gg));
          orow[j * 16] = (__bf16)(w * gg * sg * uu);
        }
      }
    }
  }
}

// ---------------- G2: inter @ wdT, atomic combine into out -------------------
__global__ __launch_bounds__(256, 2) void g2_k(
    const __bf16* __restrict__ inter, const __bf16* __restrict__ wdT,
    float* __restrict__ out, const int* __restrict__ slot_token,
    const int* __restrict__ counts, const int* __restrict__ offs) {
  int e = blockIdx.z;
  int cnt = counts[e];
  int m0 = blockIdx.y * 128;
  if (m0 >= cnt) return;
  int n0 = blockIdx.x * 128;
  int base = offs[e];

  __shared__ __align__(16) __bf16 As[128][64];
  __shared__ __align__(16) __bf16 Bs[128][64];

  int t = threadIdx.x;
  int lane = t & 63, wv = t >> 6;
  int rbase = t >> 3;
  int kcol = (t & 7) * 8;

  const __bf16* arow[4];
#pragma unroll
  for (int i = 0; i < 4; i++) {
    int gm = m0 + rbase + i * 32;
    arow[i] = inter + (size_t)(base + min(gm, cnt - 1)) * INTER_D + kcol;
  }
  const __bf16* brow = wdT + ((size_t)e * HID + n0 + rbase) * INTER_D + kcol;

  char* lA = (char*)&As[0][0] + wv * 1024;
  char* lB = (char*)&Bs[0][0] + wv * 1024;

  f32x4 acc[16];
  f32x4 zero = {0.f, 0.f, 0.f, 0.f};
#pragma unroll
  for (int i = 0; i < 16; i++) acc[i] = zero;

  int wm = (wv & 1) * 64, wn = (wv >> 1) * 64;
  int fr = lane & 15, quad = lane >> 4;

  for (int kt = 0; kt < INTER_D / 64; kt++) {
    int k0 = kt * 64;
#pragma unroll
    for (int i = 0; i < 4; i++) {
      async16(arow[i] + k0, lA + i * 4096);
      async16(brow + (size_t)(i * 32) * INTER_D + k0, lB + i * 4096);
    }
    __syncthreads();
#pragma unroll
    for (int kk = 0; kk < 2; kk++) {
      bf16x8 a[4], b[4];
#pragma unroll
      for (int i = 0; i < 4; i++) {
        a[i] = *(const bf16x8*)&As[wm + i * 16 + fr][kk * 32 + quad * 8];
        b[i] = *(const bf16x8*)&Bs[wn + i * 16 + fr][kk * 32 + quad * 8];
      }
#pragma unroll
      for (int i = 0; i < 4; i++)
#pragma unroll
        for (int j = 0; j < 4; j++) acc[i * 4 + j] = MFMA(a[i], b[j], acc[i * 4 + j]);
    }
    __syncthreads();
  }

#pragma unroll
  for (int i = 0; i < 4; i++) {
#pragma unroll
    for (int r = 0; r < 4; r++) {
      int gm = m0 + wm + i * 16 + quad * 4 + r;
      if (gm < cnt) {
        int tok = slot_token[base + gm];
        float* orow = out + (size_t)tok * HID + n0 + wn + fr;
#pragma unroll
        for (int j = 0; j < 4; j++) atomicAdd(&orow[j * 16], acc[i * 4 + j][r]);
      }
    }
  }
}

extern "C" void kernel_launch(void* const* d_in, const int* in_sizes, int n_in,
                              void* d_out, int out_size, void* d_ws, size_t ws_size,
                              hipStream_t stream) {
  const float* x = (const float*)d_in[0];
  const float* rw = (const float*)d_in[1];
  const float* wg = (const float*)d_in[2];
  const float* wu = (const float*)d_in[3];
  const float* wd = (const float*)d_in[4];
  float* out = (float*)d_out;
  char* ws = (char*)d_ws;

  if (ws_size < WS_NEED) return;  // visible failure instead of corruption

  __bf16* xb = (__bf16*)(ws + XB_OFF);
  __bf16* wgT = (__bf16*)(ws + WGT_OFF);
  __bf16* wuT = (__bf16*)(ws + WUT_OFF);
  __bf16* wdT = (__bf16*)(ws + WDT_OFF);
  __bf16* inter = (__bf16*)(ws + INTER_OFF);
  int* slot_token = (int*)(ws + ST_OFF);
  float* slot_w = (float*)(ws + SW_OFF);
  int* topk_idx = (int*)(ws + TI_OFF);
  float* topk_w = (float*)(ws + TW_OFF);
  int* counts = (int*)(ws + CTRL_OFF);
  int* offs = (int*)(ws + CTRL_OFF + 64);
  int* cursor = (int*)(ws + CTRL_OFF + 128);

  hipMemsetAsync(d_out, 0, (size_t)T_TOK * HID * sizeof(float), stream);
  hipMemsetAsync(ws + CTRL_OFF, 0, 256, stream);

  router_k<<<T_TOK, 64, 0, stream>>>(x, rw, topk_idx, topk_w, counts);
  offsets_k<<<1, 64, 0, stream>>>(counts, offs, cursor);
  scatter_k<<<T_TOK / 256, 256, 0, stream>>>(topk_idx, topk_w, cursor, slot_token, slot_w);
  cvtx_k<<<(T_TOK * HID / 4) / 256, 256, 0, stream>>>(x, xb);
  transpose_k<<<dim3(INTER_D / 32, HID / 32, NEXP), dim3(32, 8), 0, stream>>>(wg, wgT, HID, INTER_D);
  transpose_k<<<dim3(INTER_D / 32, HID / 32, NEXP), dim3(32, 8), 0, stream>>>(wu, wuT, HID, INTER_D);
  transpose_k<<<dim3(HID / 32, INTER_D / 32, NEXP), dim3(32, 8), 0, stream>>>(wd, wdT, INTER_D, HID);
  g1_k<<<dim3(INTER_D / 128, T_TOK / 128, NEXP), 256, 0, stream>>>(
      xb, wgT, wuT, inter, slot_token, slot_w, counts, offs);
  g2_k<<<dim3(HID / 128, T_TOK / 128, NEXP), 256, 0, stream>>>(
      inter, wdT, out, slot_token, counts, offs);
}

// Round 2
// 968.532 us; speedup vs baseline: 1.0649x; 1.0649x over previous
//
#include <hip/hip_runtime.h>
#include <hip/hip_bf16.h>
#include <cmath>

#define T_TOK 8192
#define HID 1024
#define INTER_D 2816
#define NEXP 8
#define NSLOT (T_TOK * 2)

typedef __bf16 bf16x8 __attribute__((ext_vector_type(8)));
typedef __bf16 bf16x4 __attribute__((ext_vector_type(4)));
typedef float f32x4 __attribute__((ext_vector_type(4)));

#define MFMA(a, b, c) __builtin_amdgcn_mfma_f32_16x16x32_bf16(a, b, c, 0, 0, 0)

// ---- workspace layout (bytes) ----
#define XB_OFF    ((size_t)0)                       // bf16 x [T][H]           16.8 MB
#define WGT_OFF   ((size_t)16777216)                // bf16 wgT [E][I][H]      46.1 MB
#define WUT_OFF   ((size_t)62914560)                // bf16 wuT [E][I][H]      46.1 MB
#define WDT_OFF   ((size_t)109051904)               // bf16 wdT [E][H][I]      46.1 MB
#define INTER_OFF ((size_t)155189248)               // bf16 inter [S][I]       92.3 MB
#define ST_OFF    ((size_t)247463936)               // int slot_token[S]
#define SW_OFF    ((size_t)247529472)               // float slot_w[S]
#define TI_OFF    ((size_t)247595008)               // int topk_idx[T][2]
#define TW_OFF    ((size_t)247660544)               // float topk_w[T][2]
#define CTRL_OFF  ((size_t)247726080)               // counts@0, offs@64, cursor@128
#define WS_NEED   ((size_t)247726336)

__device__ __forceinline__ void async16(const void* g, void* l) {
  __builtin_amdgcn_global_load_lds(
      (const __attribute__((address_space(1))) unsigned int*)g,
      (__attribute__((address_space(3))) unsigned int*)l, 16, 0, 0);
}

// ---------------- router: logits (fp64 accum), top-2, renorm weights --------
__global__ void router_k(const float* __restrict__ x, const float* __restrict__ rw,
                         int* __restrict__ topk_idx, float* __restrict__ topk_w,
                         int* __restrict__ counts) {
  int t = blockIdx.x;
  int lane = threadIdx.x;
  double acc[NEXP];
#pragma unroll
  for (int e = 0; e < NEXP; e++) acc[e] = 0.0;
  const float* xr = x + (size_t)t * HID;
  for (int kk = 0; kk < HID / 64; kk++) {
    int k = kk * 64 + lane;
    double xv = (double)xr[k];
#pragma unroll
    for (int e = 0; e < NEXP; e++) acc[e] += xv * (double)rw[k * NEXP + e];
  }
#pragma unroll
  for (int off = 32; off >= 1; off >>= 1)
#pragma unroll
    for (int e = 0; e < NEXP; e++) acc[e] += __shfl_xor(acc[e], off);
  if (lane == 0) {
    int i0 = 0;
    double v0 = acc[0];
    for (int e = 1; e < NEXP; e++)
      if (acc[e] > v0) { v0 = acc[e]; i0 = e; }
    int i1 = -1;
    double v1 = -1e300;
    for (int e = 0; e < NEXP; e++)
      if (e != i0 && acc[e] > v1) { v1 = acc[e]; i1 = e; }
    double w0 = 1.0 / (1.0 + exp(v1 - v0));
    topk_idx[2 * t] = i0;
    topk_idx[2 * t + 1] = i1;
    topk_w[2 * t] = (float)w0;
    topk_w[2 * t + 1] = (float)(1.0 - w0);
    atomicAdd(&counts[i0], 1);
    atomicAdd(&counts[i1], 1);
  }
}

__global__ void offsets_k(const int* __restrict__ counts, int* __restrict__ offs,
                          int* __restrict__ cursor) {
  if (threadIdx.x == 0) {
    int s = 0;
    for (int e = 0; e < NEXP; e++) {
      offs[e] = s;
      cursor[e] = s;
      s += counts[e];
    }
    offs[NEXP] = s;
  }
}

__global__ void scatter_k(const int* __restrict__ topk_idx, const float* __restrict__ topk_w,
                          int* __restrict__ cursor, int* __restrict__ slot_token,
                          float* __restrict__ slot_w) {
  int t = blockIdx.x * blockDim.x + threadIdx.x;
  if (t >= T_TOK) return;
#pragma unroll
  for (int k = 0; k < 2; k++) {
    int e = topk_idx[2 * t + k];
    int pos = atomicAdd(&cursor[e], 1);
    slot_token[pos] = t;
    slot_w[pos] = topk_w[2 * t + k];
  }
}

// ---------------- fp32 -> bf16 convert (x) ----------------------------------
__global__ void cvtx_k(const float* __restrict__ x, __bf16* __restrict__ xb) {
  int i = blockIdx.x * blockDim.x + threadIdx.x;
  float4 v = ((const float4*)x)[i];
  bf16x4 o;
  o[0] = (__bf16)v.x;
  o[1] = (__bf16)v.y;
  o[2] = (__bf16)v.z;
  o[3] = (__bf16)v.w;
  ((bf16x4*)xb)[i] = o;
}

// ---- transpose + convert: in fp32 [R][C] -> out bf16 [C][R] ----------------
// 32-row x 128-col tiles, float4 coalesced loads, bf16x8 (16B) stores.
__global__ void transpose_k(const float* __restrict__ in, __bf16* __restrict__ out,
                            int R, int C) {
  __shared__ float tile[128][33];  // [c][r], +1 pad
  size_t mo = (size_t)blockIdx.z * (size_t)R * C;
  int c0 = blockIdx.x * 128, r0 = blockIdx.y * 32;
  int t = threadIdx.x;  // 256 threads
#pragma unroll
  for (int i = 0; i < 4; i++) {
    int r = (t >> 5) + i * 8;
    int c = (t & 31) * 4;
    float4 v = *(const float4*)(in + mo + (size_t)(r0 + r) * C + c0 + c);
    tile[c + 0][r] = v.x;
    tile[c + 1][r] = v.y;
    tile[c + 2][r] = v.z;
    tile[c + 3][r] = v.w;
  }
  __syncthreads();
#pragma unroll
  for (int i = 0; i < 2; i++) {
    int idx = t + i * 256;  // 0..511
    int c = idx >> 2, rc = (idx & 3) * 8;
    bf16x8 o;
#pragma unroll
    for (int j = 0; j < 8; j++) o[j] = (__bf16)tile[c][rc + j];
    *(bf16x8*)(out + mo + (size_t)(c0 + c) * R + r0 + rc) = o;
  }
}

// ---------------- G1: gathered A @ [wgT|wuT], fused swiglu+weight -> inter ---
// LDS layout XOR-swizzled: slot (row, cb) holds global colblock cb ^ (row&7),
// required because global_load_lds dest is wave-uniform + lane*16 (no padding
// possible). Readers fan each quad across all 32 banks -> 2-way max (free).
__global__ __launch_bounds__(256, 2) void g1_k(
    const __bf16* __restrict__ xb, const __bf16* __restrict__ wgT,
    const __bf16* __restrict__ wuT, __bf16* __restrict__ inter,
    const int* __restrict__ slot_token, const float* __restrict__ slot_w,
    const int* __restrict__ counts, const int* __restrict__ offs) {
  int e = blockIdx.z;
  int cnt = counts[e];
  int m0 = blockIdx.y * 128;
  if (m0 >= cnt) return;
  int n0 = blockIdx.x * 128;
  int base = offs[e];

  __shared__ __align__(16) __bf16 As[128][64];
  __shared__ __align__(16) __bf16 Bgs[128][64];
  __shared__ __align__(16) __bf16 Bus[128][64];

  int t = threadIdx.x;
  int lane = t & 63, wv = t >> 6;
  int rbase = t >> 3;                              // staging row 0..31 (+i*32)
  int kcol = (((t & 7) ^ (rbase & 7)) * 8);        // XOR-swizzled source col

  const __bf16* arow[4];
#pragma unroll
  for (int i = 0; i < 4; i++) {
    int gm = m0 + rbase + i * 32;
    int slot = base + min(gm, cnt - 1);
    arow[i] = xb + (size_t)slot_token[slot] * HID + kcol;
  }
  const __bf16* bg = wgT + ((size_t)e * INTER_D + n0 + rbase) * HID + kcol;
  const __bf16* bu = wuT + ((size_t)e * INTER_D + n0 + rbase) * HID + kcol;

  char* lA = (char*)&As[0][0] + wv * 1024;
  char* lG = (char*)&Bgs[0][0] + wv * 1024;
  char* lU = (char*)&Bus[0][0] + wv * 1024;

  f32x4 accg[16], accu[16];
  f32x4 zero = {0.f, 0.f, 0.f, 0.f};
#pragma unroll
  for (int i = 0; i < 16; i++) {
    accg[i] = zero;
    accu[i] = zero;
  }

  int wm = (wv & 1) * 64, wn = (wv >> 1) * 64;
  int fr = lane & 15, quad = lane >> 4;
  int sw = fr & 7;  // row&7 of every fragment row this lane reads

  for (int kt = 0; kt < HID / 64; kt++) {
    int k0 = kt * 64;
#pragma unroll
    for (int i = 0; i < 4; i++) {
      async16(arow[i] + k0, lA + i * 4096);
      async16(bg + (size_t)(i * 32) * HID + k0, lG + i * 4096);
      async16(bu + (size_t)(i * 32) * HID + k0, lU + i * 4096);
    }
    __syncthreads();
#pragma unroll
    for (int kk = 0; kk < 2; kk++) {
      int col0 = ((kk * 4 + quad) ^ sw) * 8;  // de-swizzled read column
      bf16x8 a[4], g[4], u[4];
#pragma unroll
      for (int i = 0; i < 4; i++) {
        a[i] = *(const bf16x8*)&As[wm + i * 16 + fr][col0];
        g[i] = *(const bf16x8*)&Bgs[wn + i * 16 + fr][col0];
        u[i] = *(const bf16x8*)&Bus[wn + i * 16 + fr][col0];
      }
#pragma unroll
      for (int i = 0; i < 4; i++)
#pragma unroll
        for (int j = 0; j < 4; j++) {
          accg[i * 4 + j] = MFMA(a[i], g[j], accg[i * 4 + j]);
          accu[i * 4 + j] = MFMA(a[i], u[j], accu[i * 4 + j]);
        }
    }
    __syncthreads();
  }

#pragma unroll
  for (int i = 0; i < 4; i++) {
#pragma unroll
    for (int r = 0; r < 4; r++) {
      int gm = m0 + wm + i * 16 + quad * 4 + r;
      if (gm < cnt) {
        int slot = base + gm;
        float w = slot_w[slot];
        __bf16* orow = inter + (size_t)slot * INTER_D + n0 + wn + fr;
#pragma unroll
        for (int j = 0; j < 4; j++) {
          float gg = accg[i * 4 + j][r];
          float uu = accu[i * 4 + j][r];
          float sg = 1.f / (1.f + __expf(-gg));
          orow[j * 16] = (__bf16)(w * gg * sg * uu);
        }
      }
    }
  }
}

// ---------------- G2: inter @ wdT, atomic combine into out -------------------
__global__ __launch_bounds__(256, 2) void g2_k(
    const __bf16* __restrict__ inter, const __bf16* __restrict__ wdT,
    float* __restrict__ out, const int* __restrict__ slot_token,
    const int* __restrict__ counts, const int* __restrict__ offs) {
  int e = blockIdx.z;
  int cnt = counts[e];
  int m0 = blockIdx.y * 128;
  if (m0 >= cnt) return;
  int n0 = blockIdx.x * 128;
  int base = offs[e];

  __shared__ __align__(16) __bf16 As[128][64];
  __shared__ __align__(16) __bf16 Bs[128][64];

  int t = threadIdx.x;
  int lane = t & 63, wv = t >> 6;
  int rbase = t >> 3;
  int kcol = (((t & 7) ^ (rbase & 7)) * 8);  // XOR-swizzled source col

  const __bf16* arow[4];
#pragma unroll
  for (int i = 0; i < 4; i++) {
    int gm = m0 + rbase + i * 32;
    arow[i] = inter + (size_t)(base + min(gm, cnt - 1)) * INTER_D + kcol;
  }
  const __bf16* brow = wdT + ((size_t)e * HID + n0 + rbase) * INTER_D + kcol;

  char* lA = (char*)&As[0][0] + wv * 1024;
  char* lB = (char*)&Bs[0][0] + wv * 1024;

  f32x4 acc[16];
  f32x4 zero = {0.f, 0.f, 0.f, 0.f};
#pragma unroll
  for (int i = 0; i < 16; i++) acc[i] = zero;

  int wm = (wv & 1) * 64, wn = (wv >> 1) * 64;
  int fr = lane & 15, quad = lane >> 4;
  int sw = fr & 7;

  for (int kt = 0; kt < INTER_D / 64; kt++) {
    int k0 = kt * 64;
#pragma unroll
    for (int i = 0; i < 4; i++) {
      async16(arow[i] + k0, lA + i * 4096);
      async16(brow + (size_t)(i * 32) * INTER_D + k0, lB + i * 4096);
    }
    __syncthreads();
#pragma unroll
    for (int kk = 0; kk < 2; kk++) {
      int col0 = ((kk * 4 + quad) ^ sw) * 8;
      bf16x8 a[4], b[4];
#pragma unroll
      for (int i = 0; i < 4; i++) {
        a[i] = *(const bf16x8*)&As[wm + i * 16 + fr][col0];
        b[i] = *(const bf16x8*)&Bs[wn + i * 16 + fr][col0];
      }
#pragma unroll
      for (int i = 0; i < 4; i++)
#pragma unroll
        for (int j = 0; j < 4; j++) acc[i * 4 + j] = MFMA(a[i], b[j], acc[i * 4 + j]);
    }
    __syncthreads();
  }

#pragma unroll
  for (int i = 0; i < 4; i++) {
#pragma unroll
    for (int r = 0; r < 4; r++) {
      int gm = m0 + wm + i * 16 + quad * 4 + r;
      if (gm < cnt) {
        int tok = slot_token[base + gm];
        float* orow = out + (size_t)tok * HID + n0 + wn + fr;
#pragma unroll
        for (int j = 0; j < 4; j++) atomicAdd(&orow[j * 16], acc[i * 4 + j][r]);
      }
    }
  }
}

extern "C" void kernel_launch(void* const* d_in, const int* in_sizes, int n_in,
                              void* d_out, int out_size, void* d_ws, size_t ws_size,
                              hipStream_t stream) {
  const float* x = (const float*)d_in[0];
  const float* rw = (const float*)d_in[1];
  const float* wg = (const float*)d_in[2];
  const float* wu = (const float*)d_in[3];
  const float* wd = (const float*)d_in[4];
  float* out = (float*)d_out;
  char* ws = (char*)d_ws;

  if (ws_size < WS_NEED) return;

  __bf16* xb = (__bf16*)(ws + XB_OFF);
  __bf16* wgT = (__bf16*)(ws + WGT_OFF);
  __bf16* wuT = (__bf16*)(ws + WUT_OFF);
  __bf16* wdT = (__bf16*)(ws + WDT_OFF);
  __bf16* inter = (__bf16*)(ws + INTER_OFF);
  int* slot_token = (int*)(ws + ST_OFF);
  float* slot_w = (float*)(ws + SW_OFF);
  int* topk_idx = (int*)(ws + TI_OFF);
  float* topk_w = (float*)(ws + TW_OFF);
  int* counts = (int*)(ws + CTRL_OFF);
  int* offs = (int*)(ws + CTRL_OFF + 64);
  int* cursor = (int*)(ws + CTRL_OFF + 128);

  hipMemsetAsync(d_out, 0, (size_t)T_TOK * HID * sizeof(float), stream);
  hipMemsetAsync(ws + CTRL_OFF, 0, 256, stream);

  router_k<<<T_TOK, 64, 0, stream>>>(x, rw, topk_idx, topk_w, counts);
  offsets_k<<<1, 64, 0, stream>>>(counts, offs, cursor);
  scatter_k<<<T_TOK / 256, 256, 0, stream>>>(topk_idx, topk_w, cursor, slot_token, slot_w);
  cvtx_k<<<(T_TOK * HID / 4) / 256, 256, 0, stream>>>(x, xb);
  transpose_k<<<dim3(INTER_D / 128, HID / 32, NEXP), 256, 0, stream>>>(wg, wgT, HID, INTER_D);
  transpose_k<<<dim3(INTER_D / 128, HID / 32, NEXP), 256, 0, stream>>>(wu, wuT, HID, INTER_D);
  transpose_k<<<dim3(HID / 128, INTER_D / 32, NEXP), 256, 0, stream>>>(wd, wdT, INTER_D, HID);
  g1_k<<<dim3(INTER_D / 128, T_TOK / 128, NEXP), 256, 0, stream>>>(
      xb, wgT, wuT, inter, slot_token, slot_w, counts, offs);
  g2_k<<<dim3(HID / 128, T_TOK / 128, NEXP), 256, 0, stream>>>(
      inter, wdT, out, slot_token, counts, offs);
}

// Round 3
// 962.669 us; speedup vs baseline: 1.0714x; 1.0061x over previous
//
#include <hip/hip_runtime.h>
#include <hip/hip_bf16.h>
#include <cmath>

#define T_TOK 8192
#define HID 1024
#define INTER_D 2816
#define NEXP 8
#define NSLOT (T_TOK * 2)

typedef __bf16 bf16x8 __attribute__((ext_vector_type(8)));
typedef __bf16 bf16x4 __attribute__((ext_vector_type(4)));
typedef float f32x4 __attribute__((ext_vector_type(4)));
typedef float f32x16 __attribute__((ext_vector_type(16)));

#define MFMA32(a, b, c) __builtin_amdgcn_mfma_f32_32x32x16_bf16(a, b, c, 0, 0, 0)

// ---- workspace layout (bytes) ----
#define XB_OFF    ((size_t)0)                       // bf16 x [T][H]           16.8 MB
#define WGT_OFF   ((size_t)16777216)                // bf16 wgT [E][I][H]      46.1 MB
#define WUT_OFF   ((size_t)62914560)                // bf16 wuT [E][I][H]      46.1 MB
#define WDT_OFF   ((size_t)109051904)               // bf16 wdT [E][H][I]      46.1 MB
#define INTER_OFF ((size_t)155189248)               // bf16 inter [S][I]       92.3 MB
#define ST_OFF    ((size_t)247463936)               // int slot_token[S]
#define SW_OFF    ((size_t)247529472)               // float slot_w[S]
#define TI_OFF    ((size_t)247595008)               // int topk_idx[T][2]
#define TW_OFF    ((size_t)247660544)               // float topk_w[T][2]
#define CTRL_OFF  ((size_t)247726080)               // counts@0, offs@64
#define WS_NEED   ((size_t)247726336)

__device__ __forceinline__ void async16(const void* g, void* l) {
  __builtin_amdgcn_global_load_lds(
      (const __attribute__((address_space(1))) unsigned int*)g,
      (__attribute__((address_space(3))) unsigned int*)l, 16, 0, 0);
}

// ---------------- router: logits (fp64 accum), top-2, renorm weights --------
__global__ void router_k(const float* __restrict__ x, const float* __restrict__ rw,
                         int* __restrict__ topk_idx, float* __restrict__ topk_w,
                         int* __restrict__ counts) {
  int t = blockIdx.x;
  int lane = threadIdx.x;
  double acc[NEXP];
#pragma unroll
  for (int e = 0; e < NEXP; e++) acc[e] = 0.0;
  const float* xr = x + (size_t)t * HID;
  for (int kk = 0; kk < HID / 64; kk++) {
    int k = kk * 64 + lane;
    double xv = (double)xr[k];
#pragma unroll
    for (int e = 0; e < NEXP; e++) acc[e] += xv * (double)rw[k * NEXP + e];
  }
#pragma unroll
  for (int off = 32; off >= 1; off >>= 1)
#pragma unroll
    for (int e = 0; e < NEXP; e++) acc[e] += __shfl_xor(acc[e], off);
  if (lane == 0) {
    int i0 = 0;
    double v0 = acc[0];
    for (int e = 1; e < NEXP; e++)
      if (acc[e] > v0) { v0 = acc[e]; i0 = e; }
    int i1 = -1;
    double v1 = -1e300;
    for (int e = 0; e < NEXP; e++)
      if (e != i0 && acc[e] > v1) { v1 = acc[e]; i1 = e; }
    double w0 = 1.0 / (1.0 + exp(v1 - v0));
    topk_idx[2 * t] = i0;
    topk_idx[2 * t + 1] = i1;
    topk_w[2 * t] = (float)w0;
    topk_w[2 * t + 1] = (float)(1.0 - w0);
    atomicAdd(&counts[i0], 1);
    atomicAdd(&counts[i1], 1);
  }
}

// ---- single-block: offsets from counts, then scatter tokens to slots -------
__global__ void scatter_k(const int* __restrict__ topk_idx, const float* __restrict__ topk_w,
                          const int* __restrict__ counts, int* __restrict__ offs,
                          int* __restrict__ slot_token, float* __restrict__ slot_w) {
  __shared__ int scur[NEXP];
  int t = threadIdx.x;  // 256
  if (t == 0) {
    int s = 0;
    for (int e = 0; e < NEXP; e++) {
      offs[e] = s;
      scur[e] = s;
      s += counts[e];
    }
  }
  __syncthreads();
  for (int i = t; i < NSLOT; i += 256) {
    int e = topk_idx[i];
    int pos = atomicAdd(&scur[e], 1);
    slot_token[pos] = i >> 1;
    slot_w[pos] = topk_w[i];
  }
}

// ---------------- fp32 -> bf16 convert (x) ----------------------------------
__global__ void cvtx_k(const float* __restrict__ x, __bf16* __restrict__ xb) {
  int i = blockIdx.x * blockDim.x + threadIdx.x;
  float4 v = ((const float4*)x)[i];
  bf16x4 o;
  o[0] = (__bf16)v.x;
  o[1] = (__bf16)v.y;
  o[2] = (__bf16)v.z;
  o[3] = (__bf16)v.w;
  ((bf16x4*)xb)[i] = o;
}

// ---- transpose + convert: in fp32 [R][C] -> out bf16 [C][R] ----------------
__global__ void transpose_k(const float* __restrict__ in, __bf16* __restrict__ out,
                            int R, int C) {
  __shared__ float tile[128][33];  // [c][r], +1 pad
  size_t mo = (size_t)blockIdx.z * (size_t)R * C;
  int c0 = blockIdx.x * 128, r0 = blockIdx.y * 32;
  int t = threadIdx.x;  // 256 threads
#pragma unroll
  for (int i = 0; i < 4; i++) {
    int r = (t >> 5) + i * 8;
    int c = (t & 31) * 4;
    float4 v = *(const float4*)(in + mo + (size_t)(r0 + r) * C + c0 + c);
    tile[c + 0][r] = v.x;
    tile[c + 1][r] = v.y;
    tile[c + 2][r] = v.z;
    tile[c + 3][r] = v.w;
  }
  __syncthreads();
#pragma unroll
  for (int i = 0; i < 2; i++) {
    int idx = t + i * 256;  // 0..511
    int c = idx >> 2, rc = (idx & 3) * 8;
    bf16x8 o;
#pragma unroll
    for (int j = 0; j < 8; j++) o[j] = (__bf16)tile[c][rc + j];
    *(bf16x8*)(out + mo + (size_t)(c0 + c) * R + r0 + rc) = o;
  }
}

// ---------------- G1: gathered A @ [wgT|wuT], fused swiglu+weight -> inter ---
// 32x32x16 MFMA. LDS XOR-swizzled (slot (row,cb) holds global colblock
// cb ^ (row&7)) since global_load_lds dest is wave-uniform + lane*16.
// Fragment maps (gfx950, m74/m101-verified family):
//   A[m=lane&31][k=8*(lane>>5)+j], B[k=8*(lane>>5)+j][n=lane&31]
//   C/D: col=lane&31, row=(reg&3)+8*(reg>>2)+4*(lane>>5)
__global__ __launch_bounds__(256, 2) void g1_k(
    const __bf16* __restrict__ xb, const __bf16* __restrict__ wgT,
    const __bf16* __restrict__ wuT, __bf16* __restrict__ inter,
    const int* __restrict__ slot_token, const float* __restrict__ slot_w,
    const int* __restrict__ counts, const int* __restrict__ offs) {
  int e = blockIdx.z;
  int cnt = counts[e];
  int m0 = blockIdx.y * 128;
  if (m0 >= cnt) return;
  int n0 = blockIdx.x * 128;
  int base = offs[e];

  __shared__ __align__(16) __bf16 As[128][64];
  __shared__ __align__(16) __bf16 Bgs[128][64];
  __shared__ __align__(16) __bf16 Bus[128][64];

  int t = threadIdx.x;
  int lane = t & 63, wv = t >> 6;
  int rbase = t >> 3;                        // staging row 0..31 (+i*32)
  int kcol = (((t & 7) ^ (rbase & 7)) * 8);  // XOR-swizzled source col

  const __bf16* arow[4];
#pragma unroll
  for (int i = 0; i < 4; i++) {
    int gm = m0 + rbase + i * 32;
    int slot = base + min(gm, cnt - 1);
    arow[i] = xb + (size_t)slot_token[slot] * HID + kcol;
  }
  const __bf16* bg = wgT + ((size_t)e * INTER_D + n0 + rbase) * HID + kcol;
  const __bf16* bu = wuT + ((size_t)e * INTER_D + n0 + rbase) * HID + kcol;

  char* lA = (char*)&As[0][0] + wv * 1024;
  char* lG = (char*)&Bgs[0][0] + wv * 1024;
  char* lU = (char*)&Bus[0][0] + wv * 1024;

  f32x16 accg[4], accu[4];
#pragma unroll
  for (int i = 0; i < 4; i++) {
    accg[i] = (f32x16)(0.f);
    accu[i] = (f32x16)(0.f);
  }

  int wm = (wv & 1) * 64, wn = (wv >> 1) * 64;
  int ln31 = lane & 31, half = lane >> 5;
  int sw = ln31 & 7;  // row&7 of every fragment row this lane reads

  for (int kt = 0; kt < HID / 64; kt++) {
    int k0 = kt * 64;
#pragma unroll
    for (int i = 0; i < 4; i++) {
      async16(arow[i] + k0, lA + i * 4096);
      async16(bg + (size_t)(i * 32) * HID + k0, lG + i * 4096);
      async16(bu + (size_t)(i * 32) * HID + k0, lU + i * 4096);
    }
    __syncthreads();
#pragma unroll
    for (int kk = 0; kk < 4; kk++) {
      int col0 = ((kk * 2 + half) ^ sw) * 8;  // de-swizzled read column
      bf16x8 a[2], g[2], u[2];
#pragma unroll
      for (int i = 0; i < 2; i++) {
        a[i] = *(const bf16x8*)&As[wm + i * 32 + ln31][col0];
        g[i] = *(const bf16x8*)&Bgs[wn + i * 32 + ln31][col0];
        u[i] = *(const bf16x8*)&Bus[wn + i * 32 + ln31][col0];
      }
#pragma unroll
      for (int i = 0; i < 2; i++)
#pragma unroll
        for (int j = 0; j < 2; j++) {
          accg[i * 2 + j] = MFMA32(a[i], g[j], accg[i * 2 + j]);
          accu[i * 2 + j] = MFMA32(a[i], u[j], accu[i * 2 + j]);
        }
    }
    __syncthreads();
  }

#pragma unroll
  for (int i = 0; i < 2; i++) {
#pragma unroll
    for (int r = 0; r < 16; r++) {
      int m_in = wm + i * 32 + (r & 3) + 8 * (r >> 2) + 4 * half;
      int gm = m0 + m_in;
      if (gm < cnt) {
        int slot = base + gm;
        float w = slot_w[slot];
        __bf16* orow = inter + (size_t)slot * INTER_D + n0 + wn + ln31;
#pragma unroll
        for (int j = 0; j < 2; j++) {
          float gg = accg[i * 2 + j][r];
          float uu = accu[i * 2 + j][r];
          float sg = 1.f / (1.f + __expf(-gg));
          orow[j * 32] = (__bf16)(w * gg * sg * uu);
        }
      }
    }
  }
}

// ---------------- G2: inter @ wdT, atomic combine into out -------------------
__global__ __launch_bounds__(256, 2) void g2_k(
    const __bf16* __restrict__ inter, const __bf16* __restrict__ wdT,
    float* __restrict__ out, const int* __restrict__ slot_token,
    const int* __restrict__ counts, const int* __restrict__ offs) {
  int e = blockIdx.z;
  int cnt = counts[e];
  int m0 = blockIdx.y * 128;
  if (m0 >= cnt) return;
  int n0 = blockIdx.x * 128;
  int base = offs[e];

  __shared__ __align__(16) __bf16 As[128][64];
  __shared__ __align__(16) __bf16 Bs[128][64];

  int t = threadIdx.x;
  int lane = t & 63, wv = t >> 6;
  int rbase = t >> 3;
  int kcol = (((t & 7) ^ (rbase & 7)) * 8);

  const __bf16* arow[4];
#pragma unroll
  for (int i = 0; i < 4; i++) {
    int gm = m0 + rbase + i * 32;
    arow[i] = inter + (size_t)(base + min(gm, cnt - 1)) * INTER_D + kcol;
  }
  const __bf16* brow = wdT + ((size_t)e * HID + n0 + rbase) * INTER_D + kcol;

  char* lA = (char*)&As[0][0] + wv * 1024;
  char* lB = (char*)&Bs[0][0] + wv * 1024;

  f32x16 acc[4];
#pragma unroll
  for (int i = 0; i < 4; i++) acc[i] = (f32x16)(0.f);

  int wm = (wv & 1) * 64, wn = (wv >> 1) * 64;
  int ln31 = lane & 31, half = lane >> 5;
  int sw = ln31 & 7;

  for (int kt = 0; kt < INTER_D / 64; kt++) {
    int k0 = kt * 64;
#pragma unroll
    for (int i = 0; i < 4; i++) {
      async16(arow[i] + k0, lA + i * 4096);
      async16(brow + (size_t)(i * 32) * INTER_D + k0, lB + i * 4096);
    }
    __syncthreads();
#pragma unroll
    for (int kk = 0; kk < 4; kk++) {
      int col0 = ((kk * 2 + half) ^ sw) * 8;
      bf16x8 a[2], b[2];
#pragma unroll
      for (int i = 0; i < 2; i++) {
        a[i] = *(const bf16x8*)&As[wm + i * 32 + ln31][col0];
        b[i] = *(const bf16x8*)&Bs[wn + i * 32 + ln31][col0];
      }
#pragma unroll
      for (int i = 0; i < 2; i++)
#pragma unroll
        for (int j = 0; j < 2; j++) acc[i * 2 + j] = MFMA32(a[i], b[j], acc[i * 2 + j]);
    }
    __syncthreads();
  }

#pragma unroll
  for (int i = 0; i < 2; i++) {
#pragma unroll
    for (int r = 0; r < 16; r++) {
      int m_in = wm + i * 32 + (r & 3) + 8 * (r >> 2) + 4 * half;
      int gm = m0 + m_in;
      if (gm < cnt) {
        int tok = slot_token[base + gm];
        float* orow = out + (size_t)tok * HID + n0 + wn + ln31;
#pragma unroll
        for (int j = 0; j < 2; j++) atomicAdd(&orow[j * 32], acc[i * 2 + j][r]);
      }
    }
  }
}

extern "C" void kernel_launch(void* const* d_in, const int* in_sizes, int n_in,
                              void* d_out, int out_size, void* d_ws, size_t ws_size,
                              hipStream_t stream) {
  const float* x = (const float*)d_in[0];
  const float* rw = (const float*)d_in[1];
  const float* wg = (const float*)d_in[2];
  const float* wu = (const float*)d_in[3];
  const float* wd = (const float*)d_in[4];
  float* out = (float*)d_out;
  char* ws = (char*)d_ws;

  if (ws_size < WS_NEED) return;

  __bf16* xb = (__bf16*)(ws + XB_OFF);
  __bf16* wgT = (__bf16*)(ws + WGT_OFF);
  __bf16* wuT = (__bf16*)(ws + WUT_OFF);
  __bf16* wdT = (__bf16*)(ws + WDT_OFF);
  __bf16* inter = (__bf16*)(ws + INTER_OFF);
  int* slot_token = (int*)(ws + ST_OFF);
  float* slot_w = (float*)(ws + SW_OFF);
  int* topk_idx = (int*)(ws + TI_OFF);
  float* topk_w = (float*)(ws + TW_OFF);
  int* counts = (int*)(ws + CTRL_OFF);
  int* offs = (int*)(ws + CTRL_OFF + 64);

  hipMemsetAsync(d_out, 0, (size_t)T_TOK * HID * sizeof(float), stream);
  hipMemsetAsync(ws + CTRL_OFF, 0, 256, stream);

  router_k<<<T_TOK, 64, 0, stream>>>(x, rw, topk_idx, topk_w, counts);
  scatter_k<<<1, 256, 0, stream>>>(topk_idx, topk_w, counts, offs, slot_token, slot_w);
  cvtx_k<<<(T_TOK * HID / 4) / 256, 256, 0, stream>>>(x, xb);
  transpose_k<<<dim3(INTER_D / 128, HID / 32, NEXP), 256, 0, stream>>>(wg, wgT, HID, INTER_D);
  transpose_k<<<dim3(INTER_D / 128, HID / 32, NEXP), 256, 0, stream>>>(wu, wuT, HID, INTER_D);
  transpose_k<<<dim3(HID / 128, INTER_D / 32, NEXP), 256, 0, stream>>>(wd, wdT, INTER_D, HID);
  g1_k<<<dim3(INTER_D / 128, T_TOK / 128, NEXP), 256, 0, stream>>>(
      xb, wgT, wuT, inter, slot_token, slot_w, counts, offs);
  g2_k<<<dim3(HID / 128, T_TOK / 128, NEXP), 256, 0, stream>>>(
      inter, wdT, out, slot_token, counts, offs);
}